// Round 2
// baseline (114.706 us; speedup 1.0000x reference)
//
#include <hip/hip_runtime.h>
#include <hip/hip_bf16.h>

#define N_TOK 4096
#define DIM   1024
#define H2V   4096
#define HV    2048
#define NE    8
#define BM    128
#define BN    64
#define BK    64
#define NTHR  256
#define KSTEPS (DIM / BK)        // 16
#define ROW_TILES (N_TOK / BM)   // 32 worst-case row tiles per expert

typedef __attribute__((ext_vector_type(4))) float  f32x4;
typedef __attribute__((ext_vector_type(2))) float  f32x2;
typedef __attribute__((ext_vector_type(8))) short  s16x8;

__device__ __forceinline__ unsigned short f2bf(float f) {
    union { __hip_bfloat16 h; unsigned short u; } v;
    v.h = __float2bfloat16(f);
    return v.u;
}

__global__ void k_init(int* __restrict__ counts) {
    if (threadIdx.x < NE) counts[threadIdx.x] = 0;
}

__global__ void k_scatter(const int* __restrict__ idx, int* __restrict__ counts,
                          unsigned short* __restrict__ slots) {
    int n = blockIdx.x * blockDim.x + threadIdx.x;
    if (n < N_TOK) {
        int e = idx[n];
        int p = atomicAdd(&counts[e], 1);   // device-scope: cross-XCD safe
        slots[e * N_TOK + p] = (unsigned short)n;
    }
}

__global__ __launch_bounds__(NTHR, 2) void k_gemm(
        const float* __restrict__ X, const float* __restrict__ W,
        const int* __restrict__ counts, const unsigned short* __restrict__ slots,
        float* __restrict__ out) {
    const int ct = blockIdx.x;          // col tile: out cols [ct*64, ct*64+64)
    const int e  = blockIdx.y >> 5;     // expert
    const int rt = blockIdx.y & 31;     // row-tile slot within expert
    const int cnt = counts[e];
    const int tbase = rt * BM;
    if (tbase >= cnt) return;           // empty slot
    const unsigned short* ids = slots + e * N_TOK;

    // As: [row][k] bf16, 128B rows, granule-XOR swizzle key (row&7)
    // Bs: [col][k] bf16 (transposed W), key ((col>>1)&7); cols 0..63 gate, 64..127 up
    __shared__ unsigned short As[BM * BK];
    __shared__ unsigned short Bs[2 * BN * BK];

    const int t    = threadIdx.x;
    const int lane = t & 63;
    const int wid  = t >> 6;
    const int wm   = wid >> 1;          // wave row 0..1 (64 rows each)
    const int wn   = wid & 1;           // wave col 0..1 (32 cols each)
    const int l16  = lane & 15;
    const int g16  = lane >> 4;

    const float* Wb = W + (size_t)e * ((size_t)DIM * H2V);

    // ---- A staging geometry: thread stages 4x (row, 8k) ----
    const float* a_src[4];
    int a_row[4], a_q0[4];
#pragma unroll
    for (int p = 0; p < 4; ++p) {
        int pp = p * NTHR + t;
        a_row[p] = pp >> 3;             // 0..127
        a_q0[p]  = pp & 7;              // k-granule 0..7
        int slot = tbase + a_row[p];
        int tok  = ids[min(slot, cnt - 1)];  // clamp: rows >= cnt discarded at epilogue
        a_src[p] = X + (size_t)tok * DIM + a_q0[p] * 8;
    }
    // ---- B staging geometry: thread stages 2x (2 cols x 8 k) micro-tiles ----
    const float* b_src[2];
    int b_c0[2], b_ko[2];
#pragma unroll
    for (int p = 0; p < 2; ++p) {
        int m2 = p * NTHR + t;          // 0..511
        int cp = m2 & 63;               // col pair
        int ko = m2 >> 6;               // k-octet 0..7
        int c0 = cp * 2;                // local col 0..126
        int gc = ct * BN + (c0 & 63) + (c0 >> 6) * HV;  // gate cols, then +2048 up cols
        b_src[p] = Wb + (size_t)(ko * 8) * H2V + gc;
        b_c0[p] = c0;
        b_ko[p] = ko;
    }

    f32x4 acc[2][4][2];
    const f32x4 zero = {0.f, 0.f, 0.f, 0.f};
#pragma unroll
    for (int g = 0; g < 2; ++g)
#pragma unroll
        for (int m = 0; m < 4; ++m)
#pragma unroll
            for (int n = 0; n < 2; ++n)
                acc[g][m][n] = zero;

    // ---- pipeline stages as lambdas (all inner indices compile-time) ----
    auto load_step = [&](f32x4 (&av)[4][2], f32x2 (&bv)[2][8], int ks) {
        const int kbase = ks * BK;
#pragma unroll
        for (int p = 0; p < 4; ++p) {
            const float* s = a_src[p] + kbase;
            av[p][0] = *(const f32x4*)(s);
            av[p][1] = *(const f32x4*)(s + 4);
        }
#pragma unroll
        for (int p = 0; p < 2; ++p) {
            const float* s = b_src[p] + (size_t)kbase * H2V;
#pragma unroll
            for (int i = 0; i < 8; ++i)
                bv[p][i] = *(const f32x2*)(s + (size_t)i * H2V);
        }
    };

    auto stage_step = [&](const f32x4 (&av)[4][2], const f32x2 (&bv)[2][8]) {
#pragma unroll
        for (int p = 0; p < 4; ++p) {
            int row = a_row[p], q0 = a_q0[p];
            unsigned short tmp[8];
#pragma unroll
            for (int i = 0; i < 4; ++i) tmp[i]     = f2bf(av[p][0][i]);
#pragma unroll
            for (int i = 0; i < 4; ++i) tmp[4 + i] = f2bf(av[p][1][i]);
            *(s16x8*)((char*)As + row * (BK * 2) + ((q0 ^ (row & 7)) << 4)) =
                *(const s16x8*)tmp;
        }
#pragma unroll
        for (int p = 0; p < 2; ++p) {
            int ko = b_ko[p];
#pragma unroll
            for (int j = 0; j < 2; ++j) {
                int c = b_c0[p] + j;
                unsigned short tmp[8];
#pragma unroll
                for (int i = 0; i < 8; ++i) tmp[i] = f2bf(bv[p][i][j]);
                *(s16x8*)((char*)Bs + c * (BK * 2) + ((ko ^ ((c >> 1) & 7)) << 4)) =
                    *(const s16x8*)tmp;
            }
        }
    };

    auto mfma_step = [&]() {
#pragma unroll
        for (int kk = 0; kk < 2; ++kk) {
            s16x8 af[4], bfr[2][2];
            const int gran = kk * 4 + g16;
#pragma unroll
            for (int m = 0; m < 4; ++m) {
                int row = wm * 64 + m * 16 + l16;
                af[m] = *(const s16x8*)((const char*)As + row * (BK * 2) +
                                        ((gran ^ (row & 7)) << 4));
            }
#pragma unroll
            for (int g = 0; g < 2; ++g)
#pragma unroll
                for (int n = 0; n < 2; ++n) {
                    int c = g * BN + wn * 32 + n * 16 + l16;
                    bfr[g][n] = *(const s16x8*)((const char*)Bs + c * (BK * 2) +
                                                ((gran ^ ((c >> 1) & 7)) << 4));
                }
#pragma unroll
            for (int g = 0; g < 2; ++g)
#pragma unroll
                for (int m = 0; m < 4; ++m)
#pragma unroll
                    for (int n = 0; n < 2; ++n)
                        acc[g][m][n] = __builtin_amdgcn_mfma_f32_16x16x32_bf16(
                            af[m], bfr[g][n], acc[g][m][n], 0, 0, 0);
        }
    };

    // ---- software-pipelined main loop: load k+1 issued before MFMA(k) ----
    f32x4 avA[4][2], avB[4][2];
    f32x2 bvA[2][8], bvB[2][8];

    load_step(avA, bvA, 0);
    for (int ks = 0; ks < KSTEPS; ks += 2) {
        __syncthreads();                     // prev MFMA frag reads done
        stage_step(avA, bvA);
        __syncthreads();                     // staging visible
        load_step(avB, bvB, ks + 1);         // in flight under MFMA (ks+1 <= 15 always)
        mfma_step();

        __syncthreads();
        stage_step(avB, bvB);
        __syncthreads();
        if (ks + 2 < KSTEPS) load_step(avA, bvA, ks + 2);
        mfma_step();
    }

    // epilogue: silu(gate) * up, scatter rows back to token ids
#pragma unroll
    for (int m = 0; m < 4; ++m) {
#pragma unroll
        for (int r = 0; r < 4; ++r) {
            int rowt = wm * 64 + m * 16 + g16 * 4 + r;   // C/D: row=(lane>>4)*4+r
            int slot = tbase + rowt;
            if (slot < cnt) {
                int tok = ids[slot];
#pragma unroll
                for (int n = 0; n < 2; ++n) {
                    int col = ct * BN + wn * 32 + n * 16 + l16;  // C/D: col=lane&15
                    float a = acc[0][m][n][r];
                    float b = acc[1][m][n][r];
                    float sg = a / (1.0f + __expf(-a));
                    out[(size_t)tok * HV + col] = sg * b;
                }
            }
        }
    }
}

extern "C" void kernel_launch(void* const* d_in, const int* in_sizes, int n_in,
                              void* d_out, int out_size, void* d_ws, size_t ws_size,
                              hipStream_t stream) {
    const float* X  = (const float*)d_in[0];
    const float* W  = (const float*)d_in[1];
    const int* idx  = (const int*)d_in[2];
    float* out      = (float*)d_out;

    int* counts = (int*)d_ws;                                     // 8 ints
    unsigned short* slots = (unsigned short*)((char*)d_ws + 64);  // E*N u16 = 64 KiB

    k_init<<<1, 64, 0, stream>>>(counts);
    k_scatter<<<N_TOK / 256, 256, 0, stream>>>(idx, counts, slots);
    dim3 grid(HV / BN, NE * ROW_TILES);
    k_gemm<<<grid, NTHR, 0, stream>>>(X, W, counts, slots, out);
}

// Round 3
// 96.593 us; speedup vs baseline: 1.1875x; 1.1875x over previous
//
#include <hip/hip_runtime.h>
#include <hip/hip_bf16.h>

#define N_TOK 4096
#define DIM   1024
#define H2V   4096
#define HV    2048
#define NE    8
#define BM    128
#define BN    64                 // output cols per block (W cols staged = 2*BN)
#define BK    64
#define NTHR  256
#define KSTEPS (DIM / BK)        // 16
#define ROW_TILES (N_TOK / BM)   // 32 worst-case row tiles per expert

// d_ws layout
#define WS_COUNTS 0
#define WS_BASE   64             // 9 ints
#define WS_SLOTS  128            // NE*N_TOK u16 = 64 KiB
#define WS_XPERM  66560          // (N_TOK+BM) rows x DIM bf16 = 8.65 MB

typedef __attribute__((ext_vector_type(4))) float  f32x4;
typedef __attribute__((ext_vector_type(8))) short  s16x8;

__device__ __forceinline__ unsigned short f2bf(float f) {
    union { __hip_bfloat16 h; unsigned short u; } v;
    v.h = __float2bfloat16(f);
    return v.u;
}

__global__ void k_init(int* __restrict__ counts) {
    if (threadIdx.x < NE) counts[threadIdx.x] = 0;
}

__global__ void k_scatter(const int* __restrict__ idx, int* __restrict__ counts,
                          unsigned short* __restrict__ slots) {
    int n = blockIdx.x * blockDim.x + threadIdx.x;
    if (n < N_TOK) {
        int e = idx[n];
        int p = atomicAdd(&counts[e], 1);
        slots[e * N_TOK + p] = (unsigned short)n;
    }
}

__global__ void k_base(const int* __restrict__ counts, int* __restrict__ base) {
    if (threadIdx.x == 0) {
        int b = 0;
#pragma unroll
        for (int e = 0; e < NE; ++e) { base[e] = b; b += counts[e]; }
        base[NE] = b;
    }
}

// gather X rows into expert-sorted bf16 X_perm; 4 rows per block
__global__ void k_gather(const float* __restrict__ X, const int* __restrict__ base,
                         const unsigned short* __restrict__ slots,
                         unsigned short* __restrict__ Xp) {
    const int r    = blockIdx.x * 4 + (threadIdx.x >> 6);
    const int lane = threadIdx.x & 63;
    int e = 0;
#pragma unroll
    for (int i = 0; i < NE - 1; ++i) if (r >= base[i + 1]) e = i + 1;
    const int tok = slots[e * N_TOK + (r - base[e])];
    const float* src = X + (size_t)tok * DIM + lane * 16;
    unsigned short* dst = Xp + (size_t)r * DIM + lane * 16;
    f32x4 v0 = *(const f32x4*)(src);
    f32x4 v1 = *(const f32x4*)(src + 4);
    f32x4 v2 = *(const f32x4*)(src + 8);
    f32x4 v3 = *(const f32x4*)(src + 12);
    unsigned short t0[8], t1[8];
#pragma unroll
    for (int i = 0; i < 4; ++i) { t0[i] = f2bf(v0[i]); t0[4 + i] = f2bf(v1[i]); }
#pragma unroll
    for (int i = 0; i < 4; ++i) { t1[i] = f2bf(v2[i]); t1[4 + i] = f2bf(v3[i]); }
    *(s16x8*)(dst)     = *(const s16x8*)t0;
    *(s16x8*)(dst + 8) = *(const s16x8*)t1;
}

__global__ __launch_bounds__(NTHR, 3) void k_gemm(
        const float* __restrict__ W, const int* __restrict__ counts,
        const int* __restrict__ base, const unsigned short* __restrict__ slots,
        const unsigned short* __restrict__ Xp, float* __restrict__ out) {
    const int ct = blockIdx.x;          // 0..31
    const int e  = blockIdx.y >> 5;
    const int rt = blockIdx.y & 31;
    const int cnt = counts[e];
    const int tbase = rt * BM;
    if (tbase >= cnt) return;
    const int row_g0 = base[e] + tbase;     // global X_perm row of tile row 0

    // As[buf]: [row][k] bf16, swizzled slot = q ^ (row&7) (written via pre-swizzled
    // global source + linear global_load_lds). Bs: [col][k] bf16 transposed W,
    // slot = ko ^ (((c>>1)^(c>>4))&7). All read/write patterns uniform 8 words/bank.
    __shared__ unsigned short As[2][BM * BK];   // 2 x 16 KiB
    __shared__ unsigned short Bs[2 * BN * BK];  // 16 KiB

    const int t    = threadIdx.x;
    const int lane = t & 63;
    const int wid  = t >> 6;
    const int wm   = wid >> 1;
    const int wn   = wid & 1;
    const int l16  = lane & 15;
    const int g16  = lane >> 4;

    // ---- A staging via global_load_lds: 4 instrs/thread, pre-swizzled source ----
    // instr j: i = wid*4+j; LDS bytes [i*1024 + lane*16]; row = i*8+(lane>>3), slot q = lane&7
    // source granule = q ^ (row&7)
    const unsigned short* aptr[4];
#pragma unroll
    for (int j = 0; j < 4; ++j) {
        int i  = wid * 4 + j;
        int rl = i * 8 + (lane >> 3);
        int qs = (lane & 7) ^ ((lane >> 3) & 7);
        aptr[j] = Xp + (size_t)(row_g0 + rl) * DIM + qs * 8;
    }
    // ---- B staging: thread loads 4 consecutive W cols x 8 k as 8 dwordx4 ----
    const int c0 = (t & 31) * 4;        // local col 0..124
    const int ko = t >> 5;              // k-octet 0..7
    const int gc = ct * BN + (c0 & 63) + (c0 >> 6) * HV;
    const float* bptr = W + (size_t)e * DIM * H2V + (size_t)(ko * 8) * H2V + gc;

    f32x4 acc[2][4][2];
    const f32x4 zero = {0.f, 0.f, 0.f, 0.f};
#pragma unroll
    for (int g = 0; g < 2; ++g)
#pragma unroll
        for (int m = 0; m < 4; ++m)
#pragma unroll
            for (int n = 0; n < 2; ++n) acc[g][m][n] = zero;

    f32x4 bv[8];

    auto issueA = [&](int ks, int buf) {
#pragma unroll
        for (int j = 0; j < 4; ++j) {
            const unsigned short* g = aptr[j] + ks * BK;
            unsigned short* l = (unsigned short*)&As[buf][(wid * 4 + j) * 512];
            __builtin_amdgcn_global_load_lds(
                (const __attribute__((address_space(1))) unsigned int*)(const void*)g,
                (__attribute__((address_space(3))) unsigned int*)(void*)l, 16, 0, 0);
        }
    };
    auto loadB = [&](int ks) {
#pragma unroll
        for (int i = 0; i < 8; ++i)
            bv[i] = *(const f32x4*)(bptr + (size_t)(ks * BK + i) * H2V);
    };
    auto storeB = [&]() {
#pragma unroll
        for (int j = 0; j < 4; ++j) {
            int c = c0 + j;
            int key = ((c >> 1) ^ (c >> 4)) & 7;
            unsigned short tmp[8];
#pragma unroll
            for (int i = 0; i < 8; ++i) tmp[i] = f2bf(bv[i][j]);
            *(s16x8*)&Bs[c * 64 + ((ko ^ key) * 8)] = *(const s16x8*)tmp;
        }
    };

    // prologue
    issueA(0, 0);
    loadB(0);

    for (int ks = 0; ks < KSTEPS; ++ks) {
        const int cur = ks & 1;
        // consumption point: A(ks) in As[cur], B(ks) in bv — drain all VMEM here
        asm volatile("s_waitcnt vmcnt(0)" ::: "memory");
        __builtin_amdgcn_s_barrier();
        storeB();                            // cvt + 4 ds_write_b128
        if (ks + 1 < KSTEPS) {
            issueA(ks + 1, cur ^ 1);         // 4 gll, in flight across next barrier
            loadB(ks + 1);                   // 8 dwordx4, in flight across next barrier
        }
        asm volatile("s_waitcnt lgkmcnt(0)" ::: "memory");
        __builtin_amdgcn_s_barrier();        // Bs + As[cur] readable; NO vmcnt drain
#pragma unroll
        for (int kk = 0; kk < 2; ++kk) {
            const int gran = kk * 4 + g16;
            s16x8 af[4], bfr[2][2];
#pragma unroll
            for (int m = 0; m < 4; ++m) {
                int row = wm * 64 + m * 16 + l16;
                af[m] = *(const s16x8*)&As[cur][row * 64 + ((gran ^ (row & 7)) * 8)];
            }
#pragma unroll
            for (int g = 0; g < 2; ++g)
#pragma unroll
                for (int n = 0; n < 2; ++n) {
                    int c = g * BN + wn * 32 + n * 16 + l16;
                    int key = ((c >> 1) ^ (c >> 4)) & 7;
                    bfr[g][n] = *(const s16x8*)&Bs[c * 64 + ((gran ^ key) * 8)];
                }
#pragma unroll
            for (int g = 0; g < 2; ++g)
#pragma unroll
                for (int m = 0; m < 4; ++m)
#pragma unroll
                    for (int n = 0; n < 2; ++n)
                        acc[g][m][n] = __builtin_amdgcn_mfma_f32_16x16x32_bf16(
                            af[m], bfr[g][n], acc[g][m][n], 0, 0, 0);
        }
    }

    // epilogue: silu(gate) * up, scatter rows to token ids
    const unsigned short* ids = slots + e * N_TOK;
#pragma unroll
    for (int m = 0; m < 4; ++m) {
#pragma unroll
        for (int r = 0; r < 4; ++r) {
            int rowt = wm * 64 + m * 16 + g16 * 4 + r;
            int slot = tbase + rowt;
            if (slot < cnt) {
                int tok = ids[slot];
#pragma unroll
                for (int n = 0; n < 2; ++n) {
                    int col = ct * BN + wn * 32 + n * 16 + l16;
                    float a = acc[0][m][n][r];
                    float b = acc[1][m][n][r];
                    float sg = a / (1.0f + __expf(-a));
                    out[(size_t)tok * HV + col] = sg * b;
                }
            }
        }
    }
}

extern "C" void kernel_launch(void* const* d_in, const int* in_sizes, int n_in,
                              void* d_out, int out_size, void* d_ws, size_t ws_size,
                              hipStream_t stream) {
    const float* X  = (const float*)d_in[0];
    const float* W  = (const float*)d_in[1];
    const int* idx  = (const int*)d_in[2];
    float* out      = (float*)d_out;

    int* counts = (int*)((char*)d_ws + WS_COUNTS);
    int* base   = (int*)((char*)d_ws + WS_BASE);
    unsigned short* slots = (unsigned short*)((char*)d_ws + WS_SLOTS);
    unsigned short* Xp    = (unsigned short*)((char*)d_ws + WS_XPERM);

    k_init<<<1, 64, 0, stream>>>(counts);
    k_scatter<<<N_TOK / 256, 256, 0, stream>>>(idx, counts, slots);
    k_base<<<1, 64, 0, stream>>>(counts, base);
    k_gather<<<N_TOK / 4, 256, 0, stream>>>(X, base, slots, Xp);
    dim3 grid(HV / BN, NE * ROW_TILES);
    k_gemm<<<grid, NTHR, 0, stream>>>(W, counts, base, slots, Xp, out);
}